// Round 7
// baseline (16845.518 us; speedup 1.0000x reference)
//
#include <hip/hip_runtime.h>

#define B_    256
#define S_    1024
#define H_    512
#define G4_   2048
#define T_    256
#define NBLK  256
#define NTHR  1024
#define BB    16          // batches per batch-group
#define NBG   16          // batch groups
#define LBN   16          // blocks per batch-group
#define HS2   260         // hi/lo plane row stride in words (256 + 4 pad)
#define GST   18          // gbuf row stride (exactly-2-per-bank atomic writes)

typedef short bf8v  __attribute__((ext_vector_type(8)));   // 8 bf16 = 4 VGPR
typedef float f4v   __attribute__((ext_vector_type(4)));
typedef int   i32x4 __attribute__((ext_vector_type(4)));

#define PERM_HI 0x07060302u   // low short = s1.hi16, high short = s0.hi16
#define PERM_LO 0x05040100u   // low short = s1.lo16, high short = s0.lo16

// ---------------------------------------------------------------------------
// W2[j][k] = dec_Whh[j][k] + dec_Wih[j]*lin_W[k]  (folds scalar x-feedback)
// ---------------------------------------------------------------------------
__global__ void fuse_dec_weights(const float* __restrict__ dec_Whh,
                                 const float* __restrict__ dec_Wih,
                                 const float* __restrict__ lin_W,
                                 float* __restrict__ W2)
{
    int idx = blockIdx.x * 256 + threadIdx.x;
    int j = idx >> 9, k = idx & 511;
    W2[idx] = fmaf(dec_Wih[j], lin_W[k], dec_Whh[idx]);
}

// fast sigmoid/tanh: v_exp + v_rcp (rel err ~1e-7, margin is 7x at 6e-5)
__device__ __forceinline__ float fsig(float x)
{
    return __builtin_amdgcn_rcpf(1.0f + __expf(-x));
}
__device__ __forceinline__ float ftanh(float x)
{
    return fmaf(-2.0f, __builtin_amdgcn_rcpf(1.0f + __expf(2.0f * x)), 1.0f);
}

// ---------------------------------------------------------------------------
// Per-bg barrier: ONE monotonic agent-scope counter (sc1/MALL), no fences.
// Validated R3/R5/R6 (absmax 6e-5).
// ---------------------------------------------------------------------------
__device__ __forceinline__ void bg_barrier(unsigned* arr, int ph)
{
    __syncthreads();
    if (threadIdx.x == 0) {
        unsigned prev = __hip_atomic_fetch_add(arr, 1u, __ATOMIC_RELAXED,
                                               __HIP_MEMORY_SCOPE_AGENT);
        const unsigned target = (unsigned)(ph + 1) * LBN;
        if (prev != target - 1u) {
            while (__hip_atomic_load(arr, __ATOMIC_RELAXED,
                                     __HIP_MEMORY_SCOPE_AGENT) < target)
                __builtin_amdgcn_s_sleep(1);
        }
    }
    __syncthreads();
}

// ---------------------------------------------------------------------------
// Persistent kernel. h in global as packed [hi16|lo16] bf16-split words.
// stage() pre-splits into separate hi/lo LDS planes (perm cost paid once).
// Gates via 3-term split-bf16 MFMA (hi*hi + lo*hi + hi*lo). Wave tiling
// R=2 rowgroups x K=4 k-chunks: each B read feeds 2 MFMA rowgroups.
// Cross-kset accumulation via ds_add_f32 into one gbuf (stride 18).
// ---------------------------------------------------------------------------
__global__ void __launch_bounds__(NTHR)
seq2seq_kernel(const float* __restrict__ inputs,
               const float* __restrict__ enc_Wih,
               const float* __restrict__ enc_Whh,
               const float* __restrict__ enc_bih,
               const float* __restrict__ enc_bhh,
               const float* __restrict__ dec_Wih,
               const float* __restrict__ dec_bih,
               const float* __restrict__ dec_bhh,
               const float* __restrict__ lin_W,
               const float* __restrict__ lin_b,
               const float* __restrict__ W2,
               unsigned* __restrict__ hA0,
               unsigned* __restrict__ hB0,
               float* __restrict__ xcor,
               unsigned* __restrict__ bars,
               float* __restrict__ out)
{
    __shared__ unsigned hs_hi[BB * HS2];     // 16.6 KB: h hi-bf16 plane
    __shared__ unsigned hs_lo[BB * HS2];     // 16.6 KB: h lo-bf16 plane
    __shared__ float gbuf[128 * GST];        // 9.2 KB: gate sums (atomic acc)

    const int tid  = threadIdx.x;
    const int w    = tid >> 6;               // wave 0..15
    const int lane = tid & 63;
    const int quad = lane >> 4;              // 0..3
    const int mn   = lane & 15;              // MFMA m/n index (row / batch)
    const int rs   = w & 3;                  // rowset 0..3 (2 rowgroups each)
    const int ks   = w >> 2;                 // kset 0..3 (128 k each)
    const int bg   = blockIdx.x & (NBG - 1);
    const int lb   = blockIdx.x >> 4;        // hidden-slice owner 0..15
    const int bgbase = bg * BB;

    unsigned* arr = bars + bg * 64;

    i32x4 Ah[2][4], Al[2][4];                // 64 VGPRs: weight frags hi/lo
    auto loadA = [&](const float* __restrict__ W) {
        #pragma unroll
        for (int p = 0; p < 2; ++p) {
            const int jl = (rs * 2 + p) * 16 + mn;      // local row 0..127
            const int gate = jl >> 5, hsub = jl & 31;
            const float* rowp = W + (size_t)(gate * H_ + lb * 32 + hsub) * H_;
            #pragma unroll
            for (int l = 0; l < 4; ++l) {
                const float* rp = rowp + ks * 128 + l * 32 + quad * 8;
                float4 f0 = *(const float4*)rp;
                float4 f1 = *(const float4*)(rp + 4);
                unsigned b0 = __float_as_uint(f0.x), b1 = __float_as_uint(f0.y);
                unsigned b2 = __float_as_uint(f0.z), b3 = __float_as_uint(f0.w);
                unsigned b4 = __float_as_uint(f1.x), b5 = __float_as_uint(f1.y);
                unsigned b6 = __float_as_uint(f1.z), b7 = __float_as_uint(f1.w);
                i32x4 hi, lo;
                hi.x = __builtin_amdgcn_perm(b1, b0, PERM_HI);
                hi.y = __builtin_amdgcn_perm(b3, b2, PERM_HI);
                hi.z = __builtin_amdgcn_perm(b5, b4, PERM_HI);
                hi.w = __builtin_amdgcn_perm(b7, b6, PERM_HI);
                float r0 = f0.x - __uint_as_float(b0 & 0xffff0000u);
                float r1 = f0.y - __uint_as_float(b1 & 0xffff0000u);
                float r2 = f0.z - __uint_as_float(b2 & 0xffff0000u);
                float r3 = f0.w - __uint_as_float(b3 & 0xffff0000u);
                float r4 = f1.x - __uint_as_float(b4 & 0xffff0000u);
                float r5 = f1.y - __uint_as_float(b5 & 0xffff0000u);
                float r6 = f1.z - __uint_as_float(b6 & 0xffff0000u);
                float r7 = f1.w - __uint_as_float(b7 & 0xffff0000u);
                lo.x = __builtin_amdgcn_perm(__float_as_uint(r1), __float_as_uint(r0), PERM_HI);
                lo.y = __builtin_amdgcn_perm(__float_as_uint(r3), __float_as_uint(r2), PERM_HI);
                lo.z = __builtin_amdgcn_perm(__float_as_uint(r5), __float_as_uint(r4), PERM_HI);
                lo.w = __builtin_amdgcn_perm(__float_as_uint(r7), __float_as_uint(r6), PERM_HI);
                Ah[p][l] = hi; Al[p][l] = lo;
            }
        }
    };

    // stage: zero gbuf + load bg's packed h (32 KB) and split into hi/lo planes
    auto stage = [&](unsigned* hsrc) {
        gbuf[tid] = 0.f; gbuf[1024 + tid] = 0.f;
        if (tid < 128 * GST - 2048) gbuf[2048 + tid] = 0.f;
        unsigned long long* s = (unsigned long long*)hsrc;
        #pragma unroll
        for (int n = 0; n < 4; ++n) {
            const int iu = n * 1024 + tid;       // 8B unit: 2 packed words
            unsigned long long v = __hip_atomic_load(s + iu,
                                       __ATOMIC_RELAXED, __HIP_MEMORY_SCOPE_AGENT);
            const int row = iu >> 8, ku = iu & 255;
            unsigned vl = (unsigned)v, vh = (unsigned)(v >> 32);
            hs_hi[row * HS2 + ku] = __builtin_amdgcn_perm(vh, vl, PERM_HI);
            hs_lo[row * HS2 + ku] = __builtin_amdgcn_perm(vh, vl, PERM_LO);
        }
    };

    // 3-term split-bf16 MFMA over this wave's 2 rowgroups x 128-k range
    auto dots = [&]() {
        f4v acc0 = {0.f, 0.f, 0.f, 0.f};
        f4v acc1 = {0.f, 0.f, 0.f, 0.f};
        #pragma unroll
        for (int l = 0; l < 4; ++l) {
            const int boff = mn * HS2 + ks * 64 + l * 16 + quad * 4;
            i32x4 bhv = *(const i32x4*)(hs_hi + boff);
            i32x4 blv = *(const i32x4*)(hs_lo + boff);
            bf8v bh = __builtin_bit_cast(bf8v, bhv);
            bf8v bl = __builtin_bit_cast(bf8v, blv);
            bf8v a0h = __builtin_bit_cast(bf8v, Ah[0][l]);
            bf8v a0l = __builtin_bit_cast(bf8v, Al[0][l]);
            bf8v a1h = __builtin_bit_cast(bf8v, Ah[1][l]);
            bf8v a1l = __builtin_bit_cast(bf8v, Al[1][l]);
            acc0 = __builtin_amdgcn_mfma_f32_16x16x32_bf16(a0h, bh, acc0, 0, 0, 0);
            acc1 = __builtin_amdgcn_mfma_f32_16x16x32_bf16(a1h, bh, acc1, 0, 0, 0);
            acc0 = __builtin_amdgcn_mfma_f32_16x16x32_bf16(a0l, bh, acc0, 0, 0, 0);
            acc1 = __builtin_amdgcn_mfma_f32_16x16x32_bf16(a1l, bh, acc1, 0, 0, 0);
            acc0 = __builtin_amdgcn_mfma_f32_16x16x32_bf16(a0h, bl, acc0, 0, 0, 0);
            acc1 = __builtin_amdgcn_mfma_f32_16x16x32_bf16(a1h, bl, acc1, 0, 0, 0);
        }
        // C/D: col=mn (batch), row=quad*4+r; accumulate across ksets via ds_add
        #pragma unroll
        for (int r = 0; r < 4; ++r) {
            atomicAdd(&gbuf[((rs * 2 + 0) * 16 + quad * 4 + r) * GST + mn], acc0[r]);
            atomicAdd(&gbuf[((rs * 2 + 1) * 16 + quad * 4 + r) * GST + mn], acc1[r]);
        }
    };

    // h[b=w]·lin_W from hi/lo planes; result on lane 0 of the wave
    auto proj = [&]() -> float {
        const unsigned* hh = hs_hi + w * HS2 + 4 * lane;
        const unsigned* hl = hs_lo + w * HS2 + 4 * lane;
        uint4 uh = *(const uint4*)hh;
        uint4 ul = *(const uint4*)hl;
        const float4* lwp = (const float4*)(lin_W + 8 * lane);
        float4 v0 = lwp[0], v1 = lwp[1];
        #define RL(h, l) (__uint_as_float((h) << 16) + __uint_as_float((l) << 16))
        #define RH(h, l) (__uint_as_float((h) & 0xffff0000u) + __uint_as_float((l) & 0xffff0000u))
        float s = RL(uh.x, ul.x) * v0.x + RH(uh.x, ul.x) * v0.y;
        s = fmaf(RL(uh.y, ul.y), v0.z, s); s = fmaf(RH(uh.y, ul.y), v0.w, s);
        s = fmaf(RL(uh.z, ul.z), v1.x, s); s = fmaf(RH(uh.z, ul.z), v1.y, s);
        s = fmaf(RL(uh.w, ul.w), v1.z, s); s = fmaf(RH(uh.w, ul.w), v1.w, s);
        #undef RL
        #undef RH
        s += __shfl_down(s, 32); s += __shfl_down(s, 16); s += __shfl_down(s, 8);
        s += __shfl_down(s, 4);  s += __shfl_down(s, 2);  s += __shfl_down(s, 1);
        return s;
    };

    // nonlinearity-state mapping: threads 0..511 own one (hidden,batch) pair
    const int hsubN = tid & 31, bN = tid >> 5;
    const int hidN  = lb * 32 + hsubN;
    const bool stateful = (tid < 512);

    const float ewi = enc_Wih[hidN],          ewf = enc_Wih[H_ + hidN];
    const float ewg = enc_Wih[2 * H_ + hidN], ewo = enc_Wih[3 * H_ + hidN];
    const float ebi = enc_bih[hidN] + enc_bhh[hidN];
    const float ebf = enc_bih[H_ + hidN] + enc_bhh[H_ + hidN];
    const float ebg = enc_bih[2 * H_ + hidN] + enc_bhh[2 * H_ + hidN];
    const float ebo = enc_bih[3 * H_ + hidN] + enc_bhh[3 * H_ + hidN];
    const float linb = lin_b[0];

    loadA(enc_Whh);

    // packed h_0 = 0
    if (stateful)
        __hip_atomic_store(&hA0[(size_t)(bgbase + bN) * H_ + hidN], 0u,
                           __ATOMIC_RELAXED, __HIP_MEMORY_SCOPE_AGENT);

    // producer-side exact bf16 split: h -> [hi16|lo16] word
    auto packh = [](float v) -> unsigned {
        unsigned hb = __float_as_uint(v) & 0xffff0000u;
        float r = v - __uint_as_float(hb);
        return hb | (__float_as_uint(r) >> 16);
    };

    float cc = 0.f;
    unsigned* hcur = hA0;
    unsigned* hnxt = hB0;
    int ph = 0;

    // ---------------- encoder: 1024 steps ----------------
    #pragma unroll 1
    for (int t = 0; t < S_; ++t) {
        bg_barrier(arr, ph++);
        stage(hcur + (size_t)bgbase * H_);
        __syncthreads();
        dots();
        __syncthreads();
        if (stateful) {
            float xv = inputs[(size_t)(bgbase + bN) * S_ + t];
            const int gb = hsubN * GST + bN;
            float gi = gbuf[gb]            + fmaf(xv, ewi, ebi);
            float gf = gbuf[gb + 32 * GST] + fmaf(xv, ewf, ebf);
            float gg = gbuf[gb + 64 * GST] + fmaf(xv, ewg, ebg);
            float go = gbuf[gb + 96 * GST] + fmaf(xv, ewo, ebo);
            float i_ = fsig(gi), f_ = fsig(gf);
            float g_ = ftanh(gg), o_ = fsig(go);
            float cn = fmaf(f_, cc, i_ * g_);
            cc = cn;
            __hip_atomic_store(&hnxt[(size_t)(bgbase + bN) * H_ + hidN],
                               packh(o_ * ftanh(cn)),
                               __ATOMIC_RELAXED, __HIP_MEMORY_SCOPE_AGENT);
        }
        unsigned* tt = hcur; hcur = hnxt; hnxt = tt;
    }

    // ---------------- xcor phase + decoder weight/bias swap ----------------
    bg_barrier(arr, ph++);
    if (lb == 0) {          // xcor[b] = x0_true - (h_enc·lin_W + lin_b)
        stage(hcur + (size_t)bgbase * H_);
        __syncthreads();
        float s = proj();
        if (lane == 0) {
            float x0 = inputs[(size_t)(bgbase + w) * S_ + (S_ - 1)];
            __hip_atomic_store(&xcor[bgbase + w], x0 - (s + linb),
                               __ATOMIC_RELAXED, __HIP_MEMORY_SCOPE_AGENT);
        }
    }
    loadA(W2);
    const float dwi = dec_Wih[hidN],          dwf = dec_Wih[H_ + hidN];
    const float dwg = dec_Wih[2 * H_ + hidN], dwo = dec_Wih[3 * H_ + hidN];
    const float dbi = dec_bih[hidN] + dec_bhh[hidN] + dwi * linb;
    const float dbf = dec_bih[H_ + hidN] + dec_bhh[H_ + hidN] + dwf * linb;
    const float dbg = dec_bih[2 * H_ + hidN] + dec_bhh[2 * H_ + hidN] + dwg * linb;
    const float dbo = dec_bih[3 * H_ + hidN] + dec_bhh[3 * H_ + hidN] + dwo * linb;

    // ---------------- decoder: 256 steps ----------------
    #pragma unroll 1
    for (int t = 0; t < T_; ++t) {
        bg_barrier(arr, ph++);
        stage(hcur + (size_t)bgbase * H_);
        __syncthreads();
        dots();
        if (lb == 0 && t > 0) {       // out[:, t-1] = h_t·lin_W + lin_b
            float s = proj();
            if (lane == 0)
                out[(size_t)(bgbase + w) * T_ + (t - 1)] = s + linb;
        }
        __syncthreads();
        if (stateful) {
            const int gb = hsubN * GST + bN;
            float gi = gbuf[gb]            + dbi;
            float gf = gbuf[gb + 32 * GST] + dbf;
            float gg = gbuf[gb + 64 * GST] + dbg;
            float go = gbuf[gb + 96 * GST] + dbo;
            if (t == 0) {
                float xc = __hip_atomic_load(&xcor[bgbase + bN],
                                             __ATOMIC_RELAXED, __HIP_MEMORY_SCOPE_AGENT);
                gi = fmaf(xc, dwi, gi); gf = fmaf(xc, dwf, gf);
                gg = fmaf(xc, dwg, gg); go = fmaf(xc, dwo, go);
            }
            float i_ = fsig(gi), f_ = fsig(gf);
            float g_ = ftanh(gg), o_ = fsig(go);
            float cn = fmaf(f_, cc, i_ * g_);
            cc = cn;
            __hip_atomic_store(&hnxt[(size_t)(bgbase + bN) * H_ + hidN],
                               packh(o_ * ftanh(cn)),
                               __ATOMIC_RELAXED, __HIP_MEMORY_SCOPE_AGENT);
        }
        unsigned* tt = hcur; hcur = hnxt; hnxt = tt;
    }

    // ---------------- epilogue: out[:, T-1] from h_dec_256 ----------------
    bg_barrier(arr, ph++);
    if (lb == 0) {
        stage(hcur + (size_t)bgbase * H_);
        __syncthreads();
        float s = proj();
        if (lane == 0)
            out[(size_t)(bgbase + w) * T_ + (T_ - 1)] = s + linb;
    }
}

// ---------------------------------------------------------------------------
extern "C" void kernel_launch(void* const* d_in, const int* in_sizes, int n_in,
                              void* d_out, int out_size, void* d_ws, size_t ws_size,
                              hipStream_t stream)
{
    (void)in_sizes; (void)n_in; (void)out_size; (void)ws_size;

    const float* inputs  = (const float*)d_in[0];
    const float* enc_Wih = (const float*)d_in[1];
    const float* enc_Whh = (const float*)d_in[2];
    const float* enc_bih = (const float*)d_in[3];
    const float* enc_bhh = (const float*)d_in[4];
    const float* dec_Wih = (const float*)d_in[5];
    const float* dec_Whh = (const float*)d_in[6];
    const float* dec_bih = (const float*)d_in[7];
    const float* dec_bhh = (const float*)d_in[8];
    const float* lin_W   = (const float*)d_in[9];
    const float* lin_b   = (const float*)d_in[10];
    float* out = (float*)d_out;

    // ws: W2 (4MB) | hA (512KB) | hB (512KB) | xcor (1KB) | barriers (4KB)
    float* W2      = (float*)d_ws;
    unsigned* hA   = (unsigned*)(W2 + (size_t)G4_ * H_);
    unsigned* hB   = hA + (size_t)B_ * H_;
    float* xcor    = (float*)(hB + (size_t)B_ * H_);
    unsigned* bars = (unsigned*)(xcor + B_);

    hipMemsetAsync((void*)bars, 0, NBG * 64 * sizeof(unsigned), stream);

    hipLaunchKernelGGL(fuse_dec_weights, dim3((G4_ * H_) / 256), dim3(256), 0, stream,
                       dec_Whh, dec_Wih, lin_W, W2);

    void* args[] = {
        (void*)&inputs, (void*)&enc_Wih, (void*)&enc_Whh, (void*)&enc_bih, (void*)&enc_bhh,
        (void*)&dec_Wih, (void*)&dec_bih, (void*)&dec_bhh,
        (void*)&lin_W, (void*)&lin_b, (void*)&W2,
        (void*)&hA, (void*)&hB, (void*)&xcor, (void*)&bars, (void*)&out
    };
    hipLaunchCooperativeKernel((void*)seq2seq_kernel, dim3(NBLK), dim3(NTHR),
                               args, 0, stream);
}

// Round 8
// 4046.973 us; speedup vs baseline: 4.1625x; 4.1625x over previous
//
#include <hip/hip_runtime.h>

#define B_    256
#define S_    1024
#define H_    512
#define G4_   2048
#define T_    256
#define NBLK  256
#define NTHR  1024
#define BB    16          // batches per batch-group
#define NBG   16          // batch groups
#define LBN   16          // blocks per batch-group
#define HS2   260         // hi/lo plane row stride in words (256 + 4 pad)

typedef short bf8v  __attribute__((ext_vector_type(8)));   // 8 bf16 = 4 VGPR
typedef float f4v   __attribute__((ext_vector_type(4)));
typedef int   i32x4 __attribute__((ext_vector_type(4)));

#define PERM_HI 0x07060302u   // low short = s1.hi16, high short = s0.hi16
#define PERM_LO 0x05040100u   // low short = s1.lo16, high short = s0.lo16

// ---------------------------------------------------------------------------
// W2[j][k] = dec_Whh[j][k] + dec_Wih[j]*lin_W[k]  (folds scalar x-feedback)
// ---------------------------------------------------------------------------
__global__ void fuse_dec_weights(const float* __restrict__ dec_Whh,
                                 const float* __restrict__ dec_Wih,
                                 const float* __restrict__ lin_W,
                                 float* __restrict__ W2)
{
    int idx = blockIdx.x * 256 + threadIdx.x;
    int j = idx >> 9, k = idx & 511;
    W2[idx] = fmaf(dec_Wih[j], lin_W[k], dec_Whh[idx]);
}

// fast sigmoid/tanh: v_exp + v_rcp (rel err ~1e-7, margin is 7x at 6e-5)
__device__ __forceinline__ float fsig(float x)
{
    return __builtin_amdgcn_rcpf(1.0f + __expf(-x));
}
__device__ __forceinline__ float ftanh(float x)
{
    return fmaf(-2.0f, __builtin_amdgcn_rcpf(1.0f + __expf(2.0f * x)), 1.0f);
}

// ---------------------------------------------------------------------------
// Per-bg barrier: ONE monotonic agent-scope counter (sc1/MALL), no fences.
// Validated R3/R5/R6 (absmax 6e-5).
// ---------------------------------------------------------------------------
__device__ __forceinline__ void bg_barrier(unsigned* arr, int ph)
{
    __syncthreads();
    if (threadIdx.x == 0) {
        unsigned prev = __hip_atomic_fetch_add(arr, 1u, __ATOMIC_RELAXED,
                                               __HIP_MEMORY_SCOPE_AGENT);
        const unsigned target = (unsigned)(ph + 1) * LBN;
        if (prev != target - 1u) {
            while (__hip_atomic_load(arr, __ATOMIC_RELAXED,
                                     __HIP_MEMORY_SCOPE_AGENT) < target)
                __builtin_amdgcn_s_sleep(1);
        }
    }
    __syncthreads();
}

// ---------------------------------------------------------------------------
// Persistent kernel. h in global as packed [hi16|lo16] bf16-split words.
// stage() pre-splits into hi/lo LDS planes (perm cost paid once per producer).
// Gates via 3-term split-bf16 MFMA (hi*hi + lo*hi + hi*lo). Wave tiling
// R=2 rowgroups x K=4 ksets: each B read feeds 2 MFMA rowgroups. Per-kset
// private gbuf planes, PLAIN stores (NO LDS atomics — fp32 atomicAdd lowers
// to a CAS retry loop and serialized the whole R7 kernel); nonlin sums planes.
// ---------------------------------------------------------------------------
__global__ void __launch_bounds__(NTHR)
seq2seq_kernel(const float* __restrict__ inputs,
               const float* __restrict__ enc_Wih,
               const float* __restrict__ enc_Whh,
               const float* __restrict__ enc_bih,
               const float* __restrict__ enc_bhh,
               const float* __restrict__ dec_Wih,
               const float* __restrict__ dec_bih,
               const float* __restrict__ dec_bhh,
               const float* __restrict__ lin_W,
               const float* __restrict__ lin_b,
               const float* __restrict__ W2,
               unsigned* __restrict__ hA0,
               unsigned* __restrict__ hB0,
               float* __restrict__ xcor,
               unsigned* __restrict__ bars,
               float* __restrict__ out)
{
    __shared__ unsigned hs_hi[BB * HS2];     // 16.6 KB: h hi-bf16 plane
    __shared__ unsigned hs_lo[BB * HS2];     // 16.6 KB: h lo-bf16 plane
    __shared__ float gbuf[4][128][BB + 1];   // 34.8 KB: per-kset gate partials

    const int tid  = threadIdx.x;
    const int w    = tid >> 6;               // wave 0..15
    const int lane = tid & 63;
    const int quad = lane >> 4;              // 0..3
    const int mn   = lane & 15;              // MFMA m/n index (row / batch)
    const int rs   = w & 3;                  // rowset 0..3 (2 rowgroups each)
    const int ks   = w >> 2;                 // kset 0..3 (128 k each)
    const int bg   = blockIdx.x & (NBG - 1);
    const int lb   = blockIdx.x >> 4;        // hidden-slice owner 0..15
    const int bgbase = bg * BB;

    unsigned* arr = bars + bg * 64;

    i32x4 Ah[2][4], Al[2][4];                // 64 VGPRs: weight frags hi/lo
    auto loadA = [&](const float* __restrict__ W) {
        #pragma unroll
        for (int p = 0; p < 2; ++p) {
            const int jl = (rs * 2 + p) * 16 + mn;      // local row 0..127
            const int gate = jl >> 5, hsub = jl & 31;
            const float* rowp = W + (size_t)(gate * H_ + lb * 32 + hsub) * H_;
            #pragma unroll
            for (int l = 0; l < 4; ++l) {
                const float* rp = rowp + ks * 128 + l * 32 + quad * 8;
                float4 f0 = *(const float4*)rp;
                float4 f1 = *(const float4*)(rp + 4);
                unsigned b0 = __float_as_uint(f0.x), b1 = __float_as_uint(f0.y);
                unsigned b2 = __float_as_uint(f0.z), b3 = __float_as_uint(f0.w);
                unsigned b4 = __float_as_uint(f1.x), b5 = __float_as_uint(f1.y);
                unsigned b6 = __float_as_uint(f1.z), b7 = __float_as_uint(f1.w);
                i32x4 hi, lo;
                hi.x = __builtin_amdgcn_perm(b1, b0, PERM_HI);
                hi.y = __builtin_amdgcn_perm(b3, b2, PERM_HI);
                hi.z = __builtin_amdgcn_perm(b5, b4, PERM_HI);
                hi.w = __builtin_amdgcn_perm(b7, b6, PERM_HI);
                float r0 = f0.x - __uint_as_float(b0 & 0xffff0000u);
                float r1 = f0.y - __uint_as_float(b1 & 0xffff0000u);
                float r2 = f0.z - __uint_as_float(b2 & 0xffff0000u);
                float r3 = f0.w - __uint_as_float(b3 & 0xffff0000u);
                float r4 = f1.x - __uint_as_float(b4 & 0xffff0000u);
                float r5 = f1.y - __uint_as_float(b5 & 0xffff0000u);
                float r6 = f1.z - __uint_as_float(b6 & 0xffff0000u);
                float r7 = f1.w - __uint_as_float(b7 & 0xffff0000u);
                lo.x = __builtin_amdgcn_perm(__float_as_uint(r1), __float_as_uint(r0), PERM_HI);
                lo.y = __builtin_amdgcn_perm(__float_as_uint(r3), __float_as_uint(r2), PERM_HI);
                lo.z = __builtin_amdgcn_perm(__float_as_uint(r5), __float_as_uint(r4), PERM_HI);
                lo.w = __builtin_amdgcn_perm(__float_as_uint(r7), __float_as_uint(r6), PERM_HI);
                Ah[p][l] = hi; Al[p][l] = lo;
            }
        }
    };

    // stage: load bg's packed h (32 KB) and split into hi/lo planes
    auto stage = [&](unsigned* hsrc) {
        unsigned long long* s = (unsigned long long*)hsrc;
        #pragma unroll
        for (int n = 0; n < 4; ++n) {
            const int iu = n * 1024 + tid;       // 8B unit: 2 packed words
            unsigned long long v = __hip_atomic_load(s + iu,
                                       __ATOMIC_RELAXED, __HIP_MEMORY_SCOPE_AGENT);
            const int row = iu >> 8, ku = iu & 255;
            unsigned vl = (unsigned)v, vh = (unsigned)(v >> 32);
            hs_hi[row * HS2 + ku] = __builtin_amdgcn_perm(vh, vl, PERM_HI);
            hs_lo[row * HS2 + ku] = __builtin_amdgcn_perm(vh, vl, PERM_LO);
        }
    };

    // 3-term split-bf16 MFMA over this wave's 2 rowgroups x 128-k range.
    // Private plane per kset, plain stores (unique writer per (ks,row,mn)).
    auto dots = [&]() {
        f4v acc0 = {0.f, 0.f, 0.f, 0.f};
        f4v acc1 = {0.f, 0.f, 0.f, 0.f};
        #pragma unroll
        for (int l = 0; l < 4; ++l) {
            const int boff = mn * HS2 + ks * 64 + l * 16 + quad * 4;
            i32x4 bhv = *(const i32x4*)(hs_hi + boff);
            i32x4 blv = *(const i32x4*)(hs_lo + boff);
            bf8v bh = __builtin_bit_cast(bf8v, bhv);
            bf8v bl = __builtin_bit_cast(bf8v, blv);
            bf8v a0h = __builtin_bit_cast(bf8v, Ah[0][l]);
            bf8v a0l = __builtin_bit_cast(bf8v, Al[0][l]);
            bf8v a1h = __builtin_bit_cast(bf8v, Ah[1][l]);
            bf8v a1l = __builtin_bit_cast(bf8v, Al[1][l]);
            acc0 = __builtin_amdgcn_mfma_f32_16x16x32_bf16(a0h, bh, acc0, 0, 0, 0);
            acc1 = __builtin_amdgcn_mfma_f32_16x16x32_bf16(a1h, bh, acc1, 0, 0, 0);
            acc0 = __builtin_amdgcn_mfma_f32_16x16x32_bf16(a0l, bh, acc0, 0, 0, 0);
            acc1 = __builtin_amdgcn_mfma_f32_16x16x32_bf16(a1l, bh, acc1, 0, 0, 0);
            acc0 = __builtin_amdgcn_mfma_f32_16x16x32_bf16(a0h, bl, acc0, 0, 0, 0);
            acc1 = __builtin_amdgcn_mfma_f32_16x16x32_bf16(a1h, bl, acc1, 0, 0, 0);
        }
        // C/D: col=mn (batch), row=quad*4+r (verified m89/m91)
        #pragma unroll
        for (int r = 0; r < 4; ++r) {
            gbuf[ks][(rs * 2 + 0) * 16 + quad * 4 + r][mn] = acc0[r];
            gbuf[ks][(rs * 2 + 1) * 16 + quad * 4 + r][mn] = acc1[r];
        }
    };

    // h[b=w]·lin_W from hi/lo planes; result on lane 0 of the wave
    auto proj = [&]() -> float {
        const unsigned* hh = hs_hi + w * HS2 + 4 * lane;
        const unsigned* hl = hs_lo + w * HS2 + 4 * lane;
        uint4 uh = *(const uint4*)hh;
        uint4 ul = *(const uint4*)hl;
        const float4* lwp = (const float4*)(lin_W + 8 * lane);
        float4 v0 = lwp[0], v1 = lwp[1];
        #define RL(h, l) (__uint_as_float((h) << 16) + __uint_as_float((l) << 16))
        #define RH(h, l) (__uint_as_float((h) & 0xffff0000u) + __uint_as_float((l) & 0xffff0000u))
        float s = RL(uh.x, ul.x) * v0.x + RH(uh.x, ul.x) * v0.y;
        s = fmaf(RL(uh.y, ul.y), v0.z, s); s = fmaf(RH(uh.y, ul.y), v0.w, s);
        s = fmaf(RL(uh.z, ul.z), v1.x, s); s = fmaf(RH(uh.z, ul.z), v1.y, s);
        s = fmaf(RL(uh.w, ul.w), v1.z, s); s = fmaf(RH(uh.w, ul.w), v1.w, s);
        #undef RL
        #undef RH
        s += __shfl_down(s, 32); s += __shfl_down(s, 16); s += __shfl_down(s, 8);
        s += __shfl_down(s, 4);  s += __shfl_down(s, 2);  s += __shfl_down(s, 1);
        return s;
    };

    // nonlinearity-state mapping: threads 0..511 own one (hidden,batch) pair
    const int hsubN = tid & 31, bN = tid >> 5;
    const int hidN  = lb * 32 + hsubN;
    const bool stateful = (tid < 512);

    const float ewi = enc_Wih[hidN],          ewf = enc_Wih[H_ + hidN];
    const float ewg = enc_Wih[2 * H_ + hidN], ewo = enc_Wih[3 * H_ + hidN];
    const float ebi = enc_bih[hidN] + enc_bhh[hidN];
    const float ebf = enc_bih[H_ + hidN] + enc_bhh[H_ + hidN];
    const float ebg = enc_bih[2 * H_ + hidN] + enc_bhh[2 * H_ + hidN];
    const float ebo = enc_bih[3 * H_ + hidN] + enc_bhh[3 * H_ + hidN];
    const float linb = lin_b[0];

    loadA(enc_Whh);

    // packed h_0 = 0
    if (stateful)
        __hip_atomic_store(&hA0[(size_t)(bgbase + bN) * H_ + hidN], 0u,
                           __ATOMIC_RELAXED, __HIP_MEMORY_SCOPE_AGENT);

    // producer-side exact bf16 split: h -> [hi16|lo16] word
    auto packh = [](float v) -> unsigned {
        unsigned hb = __float_as_uint(v) & 0xffff0000u;
        float r = v - __uint_as_float(hb);
        return hb | (__float_as_uint(r) >> 16);
    };

    // sum the 4 kset planes for one gate row
    auto gsum = [&](int row, int b) -> float {
        return (gbuf[0][row][b] + gbuf[1][row][b])
             + (gbuf[2][row][b] + gbuf[3][row][b]);
    };

    float cc = 0.f;
    unsigned* hcur = hA0;
    unsigned* hnxt = hB0;
    int ph = 0;

    // ---------------- encoder: 1024 steps ----------------
    #pragma unroll 1
    for (int t = 0; t < S_; ++t) {
        bg_barrier(arr, ph++);
        stage(hcur + (size_t)bgbase * H_);
        __syncthreads();
        dots();
        __syncthreads();
        if (stateful) {
            float xv = inputs[(size_t)(bgbase + bN) * S_ + t];
            float gi = gsum(hsubN, bN)      + fmaf(xv, ewi, ebi);
            float gf = gsum(32 + hsubN, bN) + fmaf(xv, ewf, ebf);
            float gg = gsum(64 + hsubN, bN) + fmaf(xv, ewg, ebg);
            float go = gsum(96 + hsubN, bN) + fmaf(xv, ewo, ebo);
            float i_ = fsig(gi), f_ = fsig(gf);
            float g_ = ftanh(gg), o_ = fsig(go);
            float cn = fmaf(f_, cc, i_ * g_);
            cc = cn;
            __hip_atomic_store(&hnxt[(size_t)(bgbase + bN) * H_ + hidN],
                               packh(o_ * ftanh(cn)),
                               __ATOMIC_RELAXED, __HIP_MEMORY_SCOPE_AGENT);
        }
        unsigned* tt = hcur; hcur = hnxt; hnxt = tt;
    }

    // ---------------- xcor phase + decoder weight/bias swap ----------------
    bg_barrier(arr, ph++);
    if (lb == 0) {          // xcor[b] = x0_true - (h_enc·lin_W + lin_b)
        stage(hcur + (size_t)bgbase * H_);
        __syncthreads();
        float s = proj();
        if (lane == 0) {
            float x0 = inputs[(size_t)(bgbase + w) * S_ + (S_ - 1)];
            __hip_atomic_store(&xcor[bgbase + w], x0 - (s + linb),
                               __ATOMIC_RELAXED, __HIP_MEMORY_SCOPE_AGENT);
        }
    }
    loadA(W2);
    const float dwi = dec_Wih[hidN],          dwf = dec_Wih[H_ + hidN];
    const float dwg = dec_Wih[2 * H_ + hidN], dwo = dec_Wih[3 * H_ + hidN];
    const float dbi = dec_bih[hidN] + dec_bhh[hidN] + dwi * linb;
    const float dbf = dec_bih[H_ + hidN] + dec_bhh[H_ + hidN] + dwf * linb;
    const float dbg = dec_bih[2 * H_ + hidN] + dec_bhh[2 * H_ + hidN] + dwg * linb;
    const float dbo = dec_bih[3 * H_ + hidN] + dec_bhh[3 * H_ + hidN] + dwo * linb;

    // ---------------- decoder: 256 steps ----------------
    #pragma unroll 1
    for (int t = 0; t < T_; ++t) {
        bg_barrier(arr, ph++);
        stage(hcur + (size_t)bgbase * H_);
        __syncthreads();
        dots();
        if (lb == 0 && t > 0) {       // out[:, t-1] = h_t·lin_W + lin_b
            float s = proj();
            if (lane == 0)
                out[(size_t)(bgbase + w) * T_ + (t - 1)] = s + linb;
        }
        __syncthreads();
        if (stateful) {
            float gi = gsum(hsubN, bN)      + dbi;
            float gf = gsum(32 + hsubN, bN) + dbf;
            float gg = gsum(64 + hsubN, bN) + dbg;
            float go = gsum(96 + hsubN, bN) + dbo;
            if (t == 0) {
                float xc = __hip_atomic_load(&xcor[bgbase + bN],
                                             __ATOMIC_RELAXED, __HIP_MEMORY_SCOPE_AGENT);
                gi = fmaf(xc, dwi, gi); gf = fmaf(xc, dwf, gf);
                gg = fmaf(xc, dwg, gg); go = fmaf(xc, dwo, go);
            }
            float i_ = fsig(gi), f_ = fsig(gf);
            float g_ = ftanh(gg), o_ = fsig(go);
            float cn = fmaf(f_, cc, i_ * g_);
            cc = cn;
            __hip_atomic_store(&hnxt[(size_t)(bgbase + bN) * H_ + hidN],
                               packh(o_ * ftanh(cn)),
                               __ATOMIC_RELAXED, __HIP_MEMORY_SCOPE_AGENT);
        }
        unsigned* tt = hcur; hcur = hnxt; hnxt = tt;
    }

    // ---------------- epilogue: out[:, T-1] from h_dec_256 ----------------
    bg_barrier(arr, ph++);
    if (lb == 0) {
        stage(hcur + (size_t)bgbase * H_);
        __syncthreads();
        float s = proj();
        if (lane == 0)
            out[(size_t)(bgbase + w) * T_ + (T_ - 1)] = s + linb;
    }
}

// ---------------------------------------------------------------------------
extern "C" void kernel_launch(void* const* d_in, const int* in_sizes, int n_in,
                              void* d_out, int out_size, void* d_ws, size_t ws_size,
                              hipStream_t stream)
{
    (void)in_sizes; (void)n_in; (void)out_size; (void)ws_size;

    const float* inputs  = (const float*)d_in[0];
    const float* enc_Wih = (const float*)d_in[1];
    const float* enc_Whh = (const float*)d_in[2];
    const float* enc_bih = (const float*)d_in[3];
    const float* enc_bhh = (const float*)d_in[4];
    const float* dec_Wih = (const float*)d_in[5];
    const float* dec_Whh = (const float*)d_in[6];
    const float* dec_bih = (const float*)d_in[7];
    const float* dec_bhh = (const float*)d_in[8];
    const float* lin_W   = (const float*)d_in[9];
    const float* lin_b   = (const float*)d_in[10];
    float* out = (float*)d_out;

    // ws: W2 (4MB) | hA (512KB) | hB (512KB) | xcor (1KB) | barriers (4KB)
    float* W2      = (float*)d_ws;
    unsigned* hA   = (unsigned*)(W2 + (size_t)G4_ * H_);
    unsigned* hB   = hA + (size_t)B_ * H_;
    float* xcor    = (float*)(hB + (size_t)B_ * H_);
    unsigned* bars = (unsigned*)(xcor + B_);

    hipMemsetAsync((void*)bars, 0, NBG * 64 * sizeof(unsigned), stream);

    hipLaunchKernelGGL(fuse_dec_weights, dim3((G4_ * H_) / 256), dim3(256), 0, stream,
                       dec_Whh, dec_Wih, lin_W, W2);

    void* args[] = {
        (void*)&inputs, (void*)&enc_Wih, (void*)&enc_Whh, (void*)&enc_bih, (void*)&enc_bhh,
        (void*)&dec_Wih, (void*)&dec_bih, (void*)&dec_bhh,
        (void*)&lin_W, (void*)&lin_b, (void*)&W2,
        (void*)&hA, (void*)&hB, (void*)&xcor, (void*)&bars, (void*)&out
    };
    hipLaunchCooperativeKernel((void*)seq2seq_kernel, dim3(NBLK), dim3(NTHR),
                               args, 0, stream);
}

// Round 9
// 3706.115 us; speedup vs baseline: 4.5453x; 1.0920x over previous
//
#include <hip/hip_runtime.h>

#define B_    256
#define S_    1024
#define H_    512
#define G4_   2048
#define T_    256
#define NBLK  256
#define NTHR  1024
#define BB    16          // batches per batch-group
#define NBG   16          // batch groups
#define LBN   16          // blocks per batch-group
#define HS2   260         // hi/lo plane row stride in words (256 + 4 pad)
#define AUXC  0x11        // CPol sc0|sc1: coherent read at MALL (agent scope)

typedef short bf8v  __attribute__((ext_vector_type(8)));   // 8 bf16 = 4 VGPR
typedef float f4v   __attribute__((ext_vector_type(4)));
typedef int   i32x4 __attribute__((ext_vector_type(4)));

typedef const __attribute__((address_space(1))) void gas_void;
typedef __attribute__((address_space(3))) void       las_void;

#define PERM_HI 0x07060302u   // [src0.hi16 | src1.hi16] (low short = src1.hi16)

// ---------------------------------------------------------------------------
// W2[j][k] = dec_Whh[j][k] + dec_Wih[j]*lin_W[k]; dbias[j] = dec biases fused
// ---------------------------------------------------------------------------
__global__ void fuse_dec_weights(const float* __restrict__ dec_Whh,
                                 const float* __restrict__ dec_Wih,
                                 const float* __restrict__ lin_W,
                                 const float* __restrict__ dec_bih,
                                 const float* __restrict__ dec_bhh,
                                 const float* __restrict__ lin_b,
                                 float* __restrict__ W2,
                                 float* __restrict__ dbias)
{
    int idx = blockIdx.x * 256 + threadIdx.x;
    int j = idx >> 9, k = idx & 511;
    W2[idx] = fmaf(dec_Wih[j], lin_W[k], dec_Whh[idx]);
    if (idx < G4_)
        dbias[idx] = dec_bih[idx] + dec_bhh[idx] + dec_Wih[idx] * lin_b[0];
}

// fast sigmoid/tanh: v_exp + v_rcp (rel err ~1e-7; margin 7x at 6e-5)
__device__ __forceinline__ float fsig(float x)
{
    return __builtin_amdgcn_rcpf(1.0f + __expf(-x));
}
__device__ __forceinline__ float ftanh(float x)
{
    return fmaf(-2.0f, __builtin_amdgcn_rcpf(1.0f + __expf(2.0f * x)), 1.0f);
}

// ---------------------------------------------------------------------------
// Per-bg barrier: ONE monotonic agent-scope counter (sc1/MALL), no fences.
// Validated R3/R5/R6/R8 (absmax 6e-5).
// ---------------------------------------------------------------------------
__device__ __forceinline__ void bg_barrier(unsigned* arr, int ph)
{
    __syncthreads();
    if (threadIdx.x == 0) {
        unsigned prev = __hip_atomic_fetch_add(arr, 1u, __ATOMIC_RELAXED,
                                               __HIP_MEMORY_SCOPE_AGENT);
        const unsigned target = (unsigned)(ph + 1) * LBN;
        if (prev != target - 1u) {
            while (__hip_atomic_load(arr, __ATOMIC_RELAXED,
                                     __HIP_MEMORY_SCOPE_AGENT) < target)
                __builtin_amdgcn_s_sleep(1);
        }
    }
    __syncthreads();
}

// ---------------------------------------------------------------------------
// Persistent kernel. h lives in global as TWO pre-split planes (hi/lo bf16
// pairs packed in u32). stage() = 2 global_load_lds per wave (async, sc0|sc1).
// MFMA row map m = hsel*4 + gate, hsub = rs*8 + 2*quad + p: the C-fragment
// thread holds all 4 gates of one (hid,batch) cell in acc[0..3] — LSTM
// nonlinearity runs directly on accumulators. Only the 4-kset reduction
// goes through LDS (b128 writes by ks<3, b128 reads by ks==3 leaders).
// ---------------------------------------------------------------------------
__global__ void __launch_bounds__(NTHR)
seq2seq_kernel(const float* __restrict__ inputs,
               const float* __restrict__ enc_Wih,
               const float* __restrict__ enc_bih,
               const float* __restrict__ enc_bhh,
               const float* __restrict__ dec_Wih,
               const float* __restrict__ lin_W,
               const float* __restrict__ lin_b,
               const float* __restrict__ enc_Whh,
               const float* __restrict__ W2,
               const float* __restrict__ dbias,
               unsigned* __restrict__ hiA, unsigned* __restrict__ loA,
               unsigned* __restrict__ hiB, unsigned* __restrict__ loB,
               float* __restrict__ xcor,
               unsigned* __restrict__ bars,
               float* __restrict__ out)
{
    __shared__ unsigned hs_hi[BB * HS2];     // 16.6 KB: h hi-bf16 plane
    __shared__ unsigned hs_lo[BB * HS2];     // 16.6 KB: h lo-bf16 plane
    __shared__ float gbuf[3 * 4 * 2 * 272];  // 26.1 KB: kset partial f4v slots

    const int tid  = threadIdx.x;
    const int w    = tid >> 6;               // wave 0..15
    const int lane = tid & 63;
    const int quad = lane >> 4;              // 0..3
    const int mn   = lane & 15;              // MFMA m/n index
    const int rs   = w & 3;                  // rowset 0..3
    const int ks   = w >> 2;                 // kset 0..3 (128 k each)
    const int bg   = blockIdx.x & (NBG - 1);
    const int lb   = blockIdx.x >> 4;        // hidden-slice owner 0..15
    const int bgbase = bg * BB;
    const bool leader = (ks == 3);

    unsigned* arr = bars + bg * 64;

    // A rows: m = mn -> gate = mn&3, hsel = mn>>2; hsub = rs*8 + 2*hsel + p
    i32x4 Ah[2][4], Al[2][4];                // 64 regs: weight frags hi/lo
    auto loadA = [&](const float* __restrict__ W) {
        #pragma unroll
        for (int p = 0; p < 2; ++p) {
            const int grow = (mn & 3) * H_ + lb * 32 + rs * 8 + 2 * (mn >> 2) + p;
            const float* rowp = W + (size_t)grow * H_ + ks * 128 + quad * 8;
            #pragma unroll
            for (int l = 0; l < 4; ++l) {
                const float* rp = rowp + l * 32;
                float4 f0 = *(const float4*)rp;
                float4 f1 = *(const float4*)(rp + 4);
                unsigned b0 = __float_as_uint(f0.x), b1 = __float_as_uint(f0.y);
                unsigned b2 = __float_as_uint(f0.z), b3 = __float_as_uint(f0.w);
                unsigned b4 = __float_as_uint(f1.x), b5 = __float_as_uint(f1.y);
                unsigned b6 = __float_as_uint(f1.z), b7 = __float_as_uint(f1.w);
                i32x4 hi, lo;
                hi.x = __builtin_amdgcn_perm(b1, b0, PERM_HI);
                hi.y = __builtin_amdgcn_perm(b3, b2, PERM_HI);
                hi.z = __builtin_amdgcn_perm(b5, b4, PERM_HI);
                hi.w = __builtin_amdgcn_perm(b7, b6, PERM_HI);
                float r0 = f0.x - __uint_as_float(b0 & 0xffff0000u);
                float r1 = f0.y - __uint_as_float(b1 & 0xffff0000u);
                float r2 = f0.z - __uint_as_float(b2 & 0xffff0000u);
                float r3 = f0.w - __uint_as_float(b3 & 0xffff0000u);
                float r4 = f1.x - __uint_as_float(b4 & 0xffff0000u);
                float r5 = f1.y - __uint_as_float(b5 & 0xffff0000u);
                float r6 = f1.z - __uint_as_float(b6 & 0xffff0000u);
                float r7 = f1.w - __uint_as_float(b7 & 0xffff0000u);
                lo.x = __builtin_amdgcn_perm(__float_as_uint(r1), __float_as_uint(r0), PERM_HI);
                lo.y = __builtin_amdgcn_perm(__float_as_uint(r3), __float_as_uint(r2), PERM_HI);
                lo.z = __builtin_amdgcn_perm(__float_as_uint(r5), __float_as_uint(r4), PERM_HI);
                lo.w = __builtin_amdgcn_perm(__float_as_uint(r7), __float_as_uint(r6), PERM_HI);
                Ah[p][l] = hi; Al[p][l] = lo;
            }
        }
    };

    // stage: wave w DMAs batch-row (bgbase+w) of both planes into LDS (async)
    auto stage = [&](const unsigned* hi_src, const unsigned* lo_src) {
        const size_t off = (size_t)(bgbase + w) * 256 + lane * 4;
        __builtin_amdgcn_global_load_lds((gas_void*)(hi_src + off),
                                         (las_void*)(hs_hi + w * HS2), 16, 0, AUXC);
        __builtin_amdgcn_global_load_lds((gas_void*)(lo_src + off),
                                         (las_void*)(hs_lo + w * HS2), 16, 0, AUXC);
    };

    // 3-term split-bf16 MFMA over 2 m-tiles x this wave's 128-k range
    auto dots = [&](f4v& acc0, f4v& acc1) {
        acc0 = f4v{0.f, 0.f, 0.f, 0.f};
        acc1 = f4v{0.f, 0.f, 0.f, 0.f};
        #pragma unroll
        for (int l = 0; l < 4; ++l) {
            const int boff = mn * HS2 + ks * 64 + l * 16 + quad * 4;
            i32x4 bhv = *(const i32x4*)(hs_hi + boff);
            i32x4 blv = *(const i32x4*)(hs_lo + boff);
            bf8v bh = __builtin_bit_cast(bf8v, bhv);
            bf8v bl = __builtin_bit_cast(bf8v, blv);
            bf8v a0h = __builtin_bit_cast(bf8v, Ah[0][l]);
            bf8v a0l = __builtin_bit_cast(bf8v, Al[0][l]);
            bf8v a1h = __builtin_bit_cast(bf8v, Ah[1][l]);
            bf8v a1l = __builtin_bit_cast(bf8v, Al[1][l]);
            acc0 = __builtin_amdgcn_mfma_f32_16x16x32_bf16(a0h, bh, acc0, 0, 0, 0);
            acc1 = __builtin_amdgcn_mfma_f32_16x16x32_bf16(a1h, bh, acc1, 0, 0, 0);
            acc0 = __builtin_amdgcn_mfma_f32_16x16x32_bf16(a0l, bh, acc0, 0, 0, 0);
            acc1 = __builtin_amdgcn_mfma_f32_16x16x32_bf16(a1l, bh, acc1, 0, 0, 0);
            acc0 = __builtin_amdgcn_mfma_f32_16x16x32_bf16(a0h, bl, acc0, 0, 0, 0);
            acc1 = __builtin_amdgcn_mfma_f32_16x16x32_bf16(a1h, bl, acc1, 0, 0, 0);
        }
    };

    auto writegb = [&](f4v a0, f4v a1) {     // ks<3 waves park partials
        float* gp = gbuf + ((ks * 4 + rs) * 2) * 272 + quad * 68 + mn * 4;
        *(f4v*)gp = a0;
        *(f4v*)(gp + 272) = a1;
    };
    auto reduceg = [&](f4v& a0, f4v& a1) {   // leader sums 3 parked + own
        const int gb = (rs * 2) * 272 + quad * 68 + mn * 4;
        a0 += *(const f4v*)(gbuf + gb);
        a0 += *(const f4v*)(gbuf + gb + 2176);
        a0 += *(const f4v*)(gbuf + gb + 4352);
        a1 += *(const f4v*)(gbuf + gb + 272);
        a1 += *(const f4v*)(gbuf + gb + 272 + 2176);
        a1 += *(const f4v*)(gbuf + gb + 272 + 4352);
    };

    // LSTM cell on an accumulator holding (i,f,g,o)
    auto lstm = [&](f4v g, float& cc) -> float {
        float i_ = fsig(g[0]), f_ = fsig(g[1]);
        float g_ = ftanh(g[2]), o_ = fsig(g[3]);
        float cn = fmaf(f_, cc, i_ * g_);
        cc = cn;
        return o_ * ftanh(cn);
    };

    // leader thread owns adjacent hid pair (hid0, hid0+1), batch mn
    const int pidx = lb * 16 + rs * 4 + quad;         // hid-pair index
    const int hid0 = lb * 32 + rs * 8 + 2 * quad;

    auto storeh = [&](unsigned* hn, unsigned* ln, float h0, float h1) {
        unsigned b0 = __float_as_uint(h0), b1 = __float_as_uint(h1);
        unsigned hiw = __builtin_amdgcn_perm(b1, b0, PERM_HI);
        float r0 = h0 - __uint_as_float(b0 & 0xffff0000u);
        float r1 = h1 - __uint_as_float(b1 & 0xffff0000u);
        unsigned low = __builtin_amdgcn_perm(__float_as_uint(r1),
                                             __float_as_uint(r0), PERM_HI);
        size_t pa = (size_t)(bgbase + mn) * 256 + pidx;
        __hip_atomic_store(hn + pa, hiw, __ATOMIC_RELAXED, __HIP_MEMORY_SCOPE_AGENT);
        __hip_atomic_store(ln + pa, low, __ATOMIC_RELAXED, __HIP_MEMORY_SCOPE_AGENT);
    };

    // h[b=w]·lin_W from hi/lo planes; result on lane 0 of the wave
    auto proj = [&]() -> float {
        const unsigned* hh = hs_hi + w * HS2 + 4 * lane;
        const unsigned* hl = hs_lo + w * HS2 + 4 * lane;
        uint4 uh = *(const uint4*)hh;
        uint4 ul = *(const uint4*)hl;
        const float4* lwp = (const float4*)(lin_W + 8 * lane);
        float4 v0 = lwp[0], v1 = lwp[1];
        #define RL(h, l) (__uint_as_float((h) << 16) + __uint_as_float((l) << 16))
        #define RH(h, l) (__uint_as_float((h) & 0xffff0000u) + __uint_as_float((l) & 0xffff0000u))
        float s = RL(uh.x, ul.x) * v0.x + RH(uh.x, ul.x) * v0.y;
        s = fmaf(RL(uh.y, ul.y), v0.z, s); s = fmaf(RH(uh.y, ul.y), v0.w, s);
        s = fmaf(RL(uh.z, ul.z), v1.x, s); s = fmaf(RH(uh.z, ul.z), v1.y, s);
        s = fmaf(RL(uh.w, ul.w), v1.z, s); s = fmaf(RH(uh.w, ul.w), v1.w, s);
        #undef RL
        #undef RH
        s += __shfl_down(s, 32); s += __shfl_down(s, 16); s += __shfl_down(s, 8);
        s += __shfl_down(s, 4);  s += __shfl_down(s, 2);  s += __shfl_down(s, 1);
        return s;
    };

    const float linb = lin_b[0];

    // encoder per-cell constants (leaders only; 16 regs)
    float encW[2][4], encB[2][4];
    if (leader) {
        #pragma unroll
        for (int p = 0; p < 2; ++p)
            #pragma unroll
            for (int g4 = 0; g4 < 4; ++g4) {
                const int j = g4 * H_ + hid0 + p;
                encW[p][g4] = enc_Wih[j];
                encB[p][g4] = enc_bih[j] + enc_bhh[j];
            }
    }

    loadA(enc_Whh);

    // h_0 = 0 (leaders cover all 512 cells per block)
    if (leader) {
        size_t pa = (size_t)(bgbase + mn) * 256 + pidx;
        __hip_atomic_store(hiA + pa, 0u, __ATOMIC_RELAXED, __HIP_MEMORY_SCOPE_AGENT);
        __hip_atomic_store(loA + pa, 0u, __ATOMIC_RELAXED, __HIP_MEMORY_SCOPE_AGENT);
    }

    float cc0 = 0.f, cc1 = 0.f;
    unsigned *hic = hiA, *loc = loA, *hin = hiB, *lon = loB;
    int ph = 0;

    // ---------------- encoder: 1024 steps ----------------
    #pragma unroll 1
    for (int t = 0; t < S_; ++t) {
        bg_barrier(arr, ph++);
        stage(hic, loc);
        float xv = leader ? inputs[(size_t)(bgbase + mn) * S_ + t] : 0.f;
        __syncthreads();
        f4v acc0, acc1;
        dots(acc0, acc1);
        if (!leader) writegb(acc0, acc1);
        __syncthreads();
        if (leader) {
            reduceg(acc0, acc1);
            #pragma unroll
            for (int g4 = 0; g4 < 4; ++g4) {
                acc0[g4] += fmaf(xv, encW[0][g4], encB[0][g4]);
                acc1[g4] += fmaf(xv, encW[1][g4], encB[1][g4]);
            }
            float h0 = lstm(acc0, cc0);
            float h1 = lstm(acc1, cc1);
            storeh(hin, lon, h0, h1);
        }
        unsigned* t1 = hic; hic = hin; hin = t1;
        unsigned* t2 = loc; loc = lon; lon = t2;
    }

    // ---------------- xcor phase + decoder weight swap ----------------
    bg_barrier(arr, ph++);
    if (lb == 0) {          // xcor[b] = x0_true - (h_enc·lin_W + lin_b)
        stage(hic, loc);
        __syncthreads();
        float s = proj();
        if (lane == 0) {
            float x0 = inputs[(size_t)(bgbase + w) * S_ + (S_ - 1)];
            __hip_atomic_store(&xcor[bgbase + w],
                               __float_as_uint(0) * 0.f + (x0 - (s + linb)),
                               __ATOMIC_RELAXED, __HIP_MEMORY_SCOPE_AGENT);
        }
    }
    loadA(W2);

    // ---------------- decoder: 256 steps ----------------
    #pragma unroll 1
    for (int t = 0; t < T_; ++t) {
        bg_barrier(arr, ph++);
        stage(hic, loc);
        f4v db0, db1;
        if (leader) {       // prefetch fused decoder biases (L1-hot)
            #pragma unroll
            for (int g4 = 0; g4 < 4; ++g4) {
                float2 d = *(const float2*)(dbias + g4 * H_ + hid0);
                db0[g4] = d.x; db1[g4] = d.y;
            }
        }
        __syncthreads();
        f4v acc0, acc1;
        dots(acc0, acc1);
        if (!leader) writegb(acc0, acc1);
        __syncthreads();
        if (lb == 0 && t > 0) {        // out[:, t-1] = h_t·lin_W + lin_b
            float s = proj();
            if (lane == 0)
                out[(size_t)(bgbase + w) * T_ + (t - 1)] = s + linb;
        }
        if (leader) {
            reduceg(acc0, acc1);
            acc0 += db0;
            acc1 += db1;
            if (t == 0) {   // true x0 correction through dec_Wih
                float xc = __hip_atomic_load(&xcor[bgbase + mn],
                                             __ATOMIC_RELAXED, __HIP_MEMORY_SCOPE_AGENT);
                #pragma unroll
                for (int g4 = 0; g4 < 4; ++g4) {
                    float2 dw = *(const float2*)(dec_Wih + g4 * H_ + hid0);
                    acc0[g4] = fmaf(xc, dw.x, acc0[g4]);
                    acc1[g4] = fmaf(xc, dw.y, acc1[g4]);
                }
            }
            float h0 = lstm(acc0, cc0);
            float h1 = lstm(acc1, cc1);
            storeh(hin, lon, h0, h1);
        }
        unsigned* t1 = hic; hic = hin; hin = t1;
        unsigned* t2 = loc; loc = lon; lon = t2;
    }

    // ---------------- epilogue: out[:, T-1] ----------------
    bg_barrier(arr, ph++);
    if (lb == 0) {
        stage(hic, loc);
        __syncthreads();
        float s = proj();
        if (lane == 0)
            out[(size_t)(bgbase + w) * T_ + (T_ - 1)] = s + linb;
    }
}

// ---------------------------------------------------------------------------
extern "C" void kernel_launch(void* const* d_in, const int* in_sizes, int n_in,
                              void* d_out, int out_size, void* d_ws, size_t ws_size,
                              hipStream_t stream)
{
    (void)in_sizes; (void)n_in; (void)out_size; (void)ws_size;

    const float* inputs  = (const float*)d_in[0];
    const float* enc_Wih = (const float*)d_in[1];
    const float* enc_Whh = (const float*)d_in[2];
    const float* enc_bih = (const float*)d_in[3];
    const float* enc_bhh = (const float*)d_in[4];
    const float* dec_Wih = (const float*)d_in[5];
    const float* dec_Whh = (const float*)d_in[6];
    const float* dec_bih = (const float*)d_in[7];
    const float* dec_bhh = (const float*)d_in[8];
    const float* lin_W   = (const float*)d_in[9];
    const float* lin_b   = (const float*)d_in[10];
    float* out = (float*)d_out;

    // ws: W2 (4MB) | dbias (8KB) | hiA|loA|hiB|loB (1MB) | xcor | bars
    float* W2      = (float*)d_ws;
    float* dbias   = W2 + (size_t)G4_ * H_;
    unsigned* hiA  = (unsigned*)(dbias + G4_);
    unsigned* loA  = hiA + (size_t)B_ * 256;
    unsigned* hiB  = loA + (size_t)B_ * 256;
    unsigned* loB  = hiB + (size_t)B_ * 256;
    float* xcor    = (float*)(loB + (size_t)B_ * 256);
    unsigned* bars = (unsigned*)(xcor + B_);

    hipMemsetAsync((void*)bars, 0, NBG * 64 * sizeof(unsigned), stream);

    hipLaunchKernelGGL(fuse_dec_weights, dim3((G4_ * H_) / 256), dim3(256), 0, stream,
                       dec_Whh, dec_Wih, lin_W, dec_bih, dec_bhh, lin_b, W2, dbias);

    void* args[] = {
        (void*)&inputs, (void*)&enc_Wih, (void*)&enc_bih, (void*)&enc_bhh,
        (void*)&dec_Wih, (void*)&lin_W, (void*)&lin_b,
        (void*)&enc_Whh, (void*)&W2, (void*)&dbias,
        (void*)&hiA, (void*)&loA, (void*)&hiB, (void*)&loB,
        (void*)&xcor, (void*)&bars, (void*)&out
    };
    hipLaunchCooperativeKernel((void*)seq2seq_kernel, dim3(NBLK), dim3(NTHR),
                               args, 0, stream);
}